// Round 16
// baseline (189.273 us; speedup 1.0000x reference)
//
#include <hip/hip_runtime.h>
#include <math.h>

#define WF 64

__device__ __forceinline__ float silu_f(float v){ return v / (1.0f + expf(-v)); }

typedef __attribute__((ext_vector_type(8))) short bf16x8;
typedef __attribute__((ext_vector_type(4))) float f32x4;

__device__ __forceinline__ void bf16split(float v, unsigned short& h, unsigned short& l){
  unsigned int b = __float_as_uint(v);
  unsigned int hh = (b + 0x8000u) >> 16;
  float hf = __uint_as_float(hh << 16);
  float lo = v - hf;
  unsigned int bl = __float_as_uint(lo);
  h = (unsigned short)hh;
  l = (unsigned short)((bl + 0x8000u) >> 16);
}

// ---------- CSR build ----------
__global__ __launch_bounds__(256) void k_count(const int* __restrict__ dst, int* __restrict__ cnt, int E){
  int e = blockIdx.x*blockDim.x + threadIdx.x;
  if (e < E) atomicAdd(&cnt[dst[e]], 1);
}

// block-local exclusive scan over chunks of 2048 (256 thr x 8 items)
__global__ __launch_bounds__(256) void k_scan1(const int* __restrict__ cnt, int* __restrict__ rowstart, int* __restrict__ bsum, int N){
  __shared__ int s[256];
  int tid = threadIdx.x;
  int base = blockIdx.x*2048 + tid*8;
  int loc[8]; int tsum = 0;
#pragma unroll
  for (int j=0;j<8;++j){ int idx=base+j; int v = (idx<N)?cnt[idx]:0; loc[j]=tsum; tsum+=v; }
  s[tid]=tsum; __syncthreads();
  for (int off=1; off<256; off<<=1){
    int v = (tid>=off)? s[tid-off] : 0;
    __syncthreads();
    s[tid] += v;
    __syncthreads();
  }
  int texc = s[tid] - tsum;
  if (tid==255) bsum[blockIdx.x] = s[255];
#pragma unroll
  for (int j=0;j<8;++j){ int idx=base+j; if (idx<N) rowstart[idx] = texc + loc[j]; }
}

// scan3: adds block prefix (from bsum), writes cursor/dinv and dxp = {di, di*x}
__global__ __launch_bounds__(256) void k_scan3(const int* __restrict__ bsum, const int* __restrict__ cnt,
                        const float* __restrict__ x,
                        int* __restrict__ rowstart, int* __restrict__ cursor,
                        float* __restrict__ dinv, float4* __restrict__ dxp,
                        int N, int E, int nb){
  __shared__ int boffs;
  int tid = threadIdx.x;
  int b = (blockIdx.x*blockDim.x) >> 11;   // uniform within block (256 <= 2048)
  if (tid < WF){
    int v = (tid < nb && tid < b) ? bsum[tid] : 0;
#pragma unroll
    for (int off=32; off; off>>=1) v += __shfl_down(v, off);
    if (tid==0) boffs = v;
  }
  __syncthreads();
  int idx = blockIdx.x*blockDim.x + tid;
  if (idx < N){
    int v = rowstart[idx] + boffs;
    rowstart[idx]=v; cursor[idx]=v;
    float di = rsqrtf((float)(cnt[idx]+1));   // +1 self-loop
    dinv[idx] = di;
    float4 o;
    o.x = di;
    o.y = di*x[3*idx+0];
    o.z = di*x[3*idx+1];
    o.w = di*x[3*idx+2];
    dxp[idx] = o;
  }
  if (idx==0) rowstart[N]=E;
}

// fill CSR: minimum scatter — one 4B colsrc write + cursor atomic per edge
__global__ __launch_bounds__(256) void k_fill(const int* __restrict__ src, const int* __restrict__ dst,
                       int* __restrict__ cursor, int* __restrict__ colsrc, int E){
  int e = blockIdx.x*blockDim.x + threadIdx.x;
  if (e < E){
    int d = dst[e];
    int pos = atomicAdd(&cursor[d], 1);
    colsrc[pos] = src[e];
  }
}

// W2 -> transposed bf16 hi/lo planes [224 f][128 k], zero-padded
__global__ __launch_bounds__(256) void k_wconv(const float* __restrict__ W2,
                       unsigned short* __restrict__ w2th, unsigned short* __restrict__ w2tl){
  int idx = blockIdx.x*blockDim.x + threadIdx.x;
  if (idx < 224*128){
    int f = idx >> 7, k = idx & 127;
    float v = (f < 200 && k < 100) ? W2[(size_t)k*200 + f] : 0.f;
    unsigned short h, l;
    bf16split(v, h, l);
    w2th[idx] = h;
    w2tl[idx] = l;
  }
}

// ---------- layer 1: CSR walk over dxp (16B gathers, 4x unroll), then @W1+b1, silu ----------
__global__ __launch_bounds__(256) void k_l1(const float4* __restrict__ dxp,
                     const int* __restrict__ rowstart, const int* __restrict__ colsrc,
                     const float* __restrict__ W1, const float* __restrict__ b1,
                     float* __restrict__ h1s, int N){
  __shared__ float w[300];
  __shared__ float bb[100];
  int tid = threadIdx.x;
  for (int t=tid; t<300; t+=blockDim.x) w[t]=W1[t];
  for (int t=tid; t<100; t+=blockDim.x) bb[t]=b1[t];
  __syncthreads();
  int i = blockIdx.x*blockDim.x + tid;
  if (i >= N) return;
  float4 self = dxp[i];
  float di = self.x;
  float sx = self.y, sy = self.z, sz = self.w;
  int jb = rowstart[i], je = rowstart[i+1];
  int j = jb;
  for (; j+3 < je; j += 4){
    float4 r0 = dxp[colsrc[j]];
    float4 r1 = dxp[colsrc[j+1]];
    float4 r2 = dxp[colsrc[j+2]];
    float4 r3 = dxp[colsrc[j+3]];
    sx += (r0.y + r1.y) + (r2.y + r3.y);
    sy += (r0.z + r1.z) + (r2.z + r3.z);
    sz += (r0.w + r1.w) + (r2.w + r3.w);
  }
  for (; j < je; ++j){
    float4 r = dxp[colsrc[j]];
    sx += r.y; sy += r.z; sz += r.w;
  }
  sx*=di; sy*=di; sz*=di;
  float* orow = h1s + (size_t)i*100;
#pragma unroll
  for (int f0=0; f0<100; f0+=4){
    float4 o;
    o.x = silu_f(sx*w[f0+0] + sy*w[100+f0+0] + sz*w[200+f0+0] + bb[f0+0]);
    o.y = silu_f(sx*w[f0+1] + sy*w[100+f0+1] + sz*w[200+f0+1] + bb[f0+1]);
    o.z = silu_f(sx*w[f0+2] + sy*w[100+f0+2] + sz*w[200+f0+2] + bb[f0+2]);
    o.w = silu_f(sx*w[f0+3] + sy*w[100+f0+3] + sz*w[200+f0+3] + bb[f0+3]);
    *(float4*)&orow[f0] = o;
  }
}

// ---------- layer 2 aggregation -> bf16 hi/lo planes [N_pad][128] ----------
// HALF-WAVE per node: lanes 0..24 own 4 feats (float4 gather per neighbor);
// lanes 25..31 zero-fill the k=100..127 pad. Split fused here (once/element).
__global__ __launch_bounds__(256) void k_agg2(const float* __restrict__ h1s, const int* __restrict__ rowstart,
                       const int* __restrict__ colsrc, const float* __restrict__ dinv,
                       unsigned short* __restrict__ a2h, unsigned short* __restrict__ a2l, int N){
  int node = blockIdx.x*8 + (threadIdx.x >> 5);
  int lane = threadIdx.x & 31;
  if (node >= N) return;
  if (lane >= 25){
    int ko = 100 + (lane-25)*4;
    ushort4 z = make_ushort4(0,0,0,0);
    *(ushort4*)(a2h + (size_t)node*128 + ko) = z;
    *(ushort4*)(a2l + (size_t)node*128 + ko) = z;
    return;
  }
  float di = dinv[node];
  float4 v = *(const float4*)(h1s + (size_t)node*100 + lane*4);
  float4 acc;
  acc.x = di*v.x; acc.y = di*v.y; acc.z = di*v.z; acc.w = di*v.w;
  int jb = rowstart[node], je = rowstart[node+1];
  int j = jb;
  for (; j+1 < je; j += 2){
    int u0 = colsrc[j];   float w0 = dinv[u0];
    int u1 = colsrc[j+1]; float w1 = dinv[u1];
    float4 r0 = *(const float4*)(h1s + (size_t)u0*100 + lane*4);
    float4 r1 = *(const float4*)(h1s + (size_t)u1*100 + lane*4);
    acc.x += w0*r0.x + w1*r1.x;
    acc.y += w0*r0.y + w1*r1.y;
    acc.z += w0*r0.z + w1*r1.z;
    acc.w += w0*r0.w + w1*r1.w;
  }
  if (j < je){
    int u = colsrc[j]; float wv = dinv[u];
    float4 r = *(const float4*)(h1s + (size_t)u*100 + lane*4);
    acc.x += wv*r.x; acc.y += wv*r.y; acc.z += wv*r.z; acc.w += wv*r.w;
  }
  float o[4] = { di*acc.x, di*acc.y, di*acc.z, di*acc.w };
  ushort4 h4, l4;
  bf16split(o[0], h4.x, l4.x);
  bf16split(o[1], h4.y, l4.y);
  bf16split(o[2], h4.z, l4.z);
  bf16split(o[3], h4.w, l4.w);
  *(ushort4*)(a2h + (size_t)node*128 + lane*4) = h4;
  *(ushort4*)(a2l + (size_t)node*128 + lane*4) = l4;
}

// ---------- layer 2 matmul via split-bf16 MFMA, A read ONCE per block ----------
// Block 128 thr = 2 waves (hipcc grants ~144-160 VGPR at 128 thr). Tile 32n.
// Each lane holds its A fragments (8 x bf16x8 = 32 VGPR) across an internal
// fb=0..6 loop over all 7 f-tiles -> A planes fetched ONCE total (~26 MB vs
// R15's 90 MB re-fetch). W planes (229 KB) are L2-resident. Per fb: 16 W
// fragment loads + 24 MFMA + LDS-pooled epilogue (8-graph window).
__global__ __launch_bounds__(128) void k_mm2(const unsigned short* __restrict__ a2h,
                      const unsigned short* __restrict__ a2l,
                      const unsigned short* __restrict__ w2th,
                      const unsigned short* __restrict__ w2tl,
                      const float* __restrict__ b2, const int* __restrict__ batch,
                      float* __restrict__ pooled, int N){
  __shared__ float plL[256];
  int tid = threadIdx.x;
  int l = tid & 63, w = tid >> 6;   // w in {0,1}
  int n0 = blockIdx.x * 32;
  int row = l & 15;
  int kg  = l >> 4;

  const unsigned short* ah_p = a2h + (size_t)(n0 + w*16 + row)*128;
  const unsigned short* al_p = a2l + (size_t)(n0 + w*16 + row)*128;

  // A fragments held in registers across the whole fb loop
  bf16x8 ahf[4], alf[4];
#pragma unroll
  for (int ks = 0; ks < 4; ++ks){
    int ko = ks*32 + kg*8;
    ahf[ks] = *(const bf16x8*)(ah_p + ko);
    alf[ks] = *(const bf16x8*)(al_p + ko);
  }

  int g0 = batch[n0];

  for (int fb = 0; fb < 7; ++fb){
    int gf0 = fb*32 + row, gf1 = gf0 + 16;
    const unsigned short* wh0_p = w2th + (size_t)gf0*128;
    const unsigned short* wl0_p = w2tl + (size_t)gf0*128;
    const unsigned short* wh1_p = w2th + (size_t)gf1*128;
    const unsigned short* wl1_p = w2tl + (size_t)gf1*128;

    f32x4 acc0 = {0.f,0.f,0.f,0.f};
    f32x4 acc1 = {0.f,0.f,0.f,0.f};
#pragma unroll
    for (int ks = 0; ks < 4; ++ks){
      int ko = ks*32 + kg*8;
      bf16x8 wh0 = *(const bf16x8*)(wh0_p + ko);
      bf16x8 wl0 = *(const bf16x8*)(wl0_p + ko);
      bf16x8 wh1 = *(const bf16x8*)(wh1_p + ko);
      bf16x8 wl1 = *(const bf16x8*)(wl1_p + ko);
      acc0 = __builtin_amdgcn_mfma_f32_16x16x32_bf16(ahf[ks], wh0, acc0, 0, 0, 0);
      acc0 = __builtin_amdgcn_mfma_f32_16x16x32_bf16(ahf[ks], wl0, acc0, 0, 0, 0);
      acc0 = __builtin_amdgcn_mfma_f32_16x16x32_bf16(alf[ks], wh0, acc0, 0, 0, 0);
      acc1 = __builtin_amdgcn_mfma_f32_16x16x32_bf16(ahf[ks], wh1, acc1, 0, 0, 0);
      acc1 = __builtin_amdgcn_mfma_f32_16x16x32_bf16(ahf[ks], wl1, acc1, 0, 0, 0);
      acc1 = __builtin_amdgcn_mfma_f32_16x16x32_bf16(alf[ks], wh1, acc1, 0, 0, 0);
    }

    // ---- epilogue for this fb: silu + LDS pooled window -> few atomics ----
    __syncthreads();                 // previous fb's flush readers done
    for (int idx = tid; idx < 256; idx += 128) plL[idx] = 0.f;
    __syncthreads();

#pragma unroll
    for (int ft = 0; ft < 2; ++ft){
      f32x4 a = ft ? acc1 : acc0;
      int fl = ft*16 + row;           // local f in [0,32)
      int gf = fb*32 + fl;
      if (gf < 200){
        float bias = b2[gf];
        float s = 0.f;
        int gprev = -1;
#pragma unroll
        for (int r = 0; r < 4; ++r){
          int node = n0 + w*16 + kg*4 + r;   // C/D row = (l>>4)*4 + r
          if (node < N){
            int g = batch[node];
            if (g != gprev){
              if (gprev >= 0){
                int dg = gprev - g0;
                if (dg < 8) atomicAdd(&plL[dg*32 + fl], s);
                else        atomicAdd(&pooled[(size_t)gprev*200 + gf], s);
              }
              gprev = g; s = 0.f;
            }
            s += silu_f(a[r] + bias);
          }
        }
        if (gprev >= 0){
          int dg = gprev - g0;
          if (dg < 8) atomicAdd(&plL[dg*32 + fl], s);
          else        atomicAdd(&pooled[(size_t)gprev*200 + gf], s);
        }
      }
    }
    __syncthreads();
    for (int idx = tid; idx < 256; idx += 128){
      float v = plL[idx];
      if (v != 0.f){
        int r = idx >> 5, f = idx & 31;
        int gf = fb*32 + f;
        if (gf < 200) atomicAdd(&pooled[(size_t)(g0+r)*200 + gf], v);
      }
    }
  }
}

// ---------- head: mean finalize + MLP, one block per graph ----------
__global__ __launch_bounds__(256) void k_head(const float* __restrict__ pooled, const int* __restrict__ batch,
                       const float* __restrict__ W3, const float* __restrict__ b3,
                       const float* __restrict__ W4, const float* __restrict__ b4,
                       float* __restrict__ out, int N){
  __shared__ float pl[200];
  __shared__ float h3[100];
  int g = blockIdx.x; int tid = threadIdx.x;
  // lower_bound(batch, g) and lower_bound(batch, g+1) to get node count
  int lo=0, hi=N;
  while (lo<hi){ int m=(lo+hi)>>1; if (batch[m] < g) lo=m+1; else hi=m; }
  int s = lo;
  hi=N;
  while (lo<hi){ int m=(lo+hi)>>1; if (batch[m] < g+1) lo=m+1; else hi=m; }
  int e = lo;
  float inv = (e>s) ? 1.0f/(float)(e-s) : 0.0f;
  if (tid < 200) pl[tid] = pooled[(size_t)g*200 + tid] * inv;
  __syncthreads();
  if (tid < 100){
    float acc = b3[tid];
    for (int k=0;k<200;++k) acc += pl[k]*W3[k*100+tid];
    h3[tid] = silu_f(acc);
  }
  __syncthreads();
  if (tid < WF){
    float p = 0.f;
    if (tid < 100)      p  = h3[tid]     * W4[tid];
    if (tid + 64 < 100) p += h3[tid+64]  * W4[tid+64];
#pragma unroll
    for (int off=32; off; off>>=1) p += __shfl_down(p, off);
    if (tid==0) out[g] = p + b4[0];
  }
}

extern "C" void kernel_launch(void* const* d_in, const int* in_sizes, int n_in,
                              void* d_out, int out_size, void* d_ws, size_t ws_size,
                              hipStream_t stream){
  const float* x  = (const float*)d_in[0];
  const int*   ei = (const int*)  d_in[1];
  const int* batch= (const int*)  d_in[2];
  const float* W1 = (const float*)d_in[4];
  const float* b1 = (const float*)d_in[5];
  const float* W2 = (const float*)d_in[6];
  const float* b2 = (const float*)d_in[7];
  const float* W3 = (const float*)d_in[8];
  const float* b3 = (const float*)d_in[9];
  const float* W4 = (const float*)d_in[10];
  const float* b4 = (const float*)d_in[11];
  float* out = (float*)d_out;

  int N = in_sizes[0]/3;
  int E = in_sizes[1]/2;
  int G = out_size;
  const int* src = ei;
  const int* dst = ei + E;
  int NP = ((N + 63)/64)*64;   // padded rows for mm2 tile overrun

  char* base = (char*)d_ws; size_t off = 0;
  auto alloc = [&](size_t bytes)->void*{
    void* p = base + off;
    off = (off + bytes + 255) & ~(size_t)255;
    return p;
  };
  // zero-init group first (single memset): cnt, pooled
  int*   cnt      = (int*)  alloc((size_t)N*4);
  float* pooled   = (float*)alloc((size_t)G*200*4);
  size_t zbytes   = off;
  int*   rowstart = (int*)  alloc((size_t)(N+1)*4);
  int*   cursor   = (int*)  alloc((size_t)N*4);
  int*   bsum     = (int*)  alloc(4096);
  int*   colsrc   = (int*)  alloc((size_t)E*4);
  float* dinv     = (float*)alloc((size_t)N*4);
  float4* dxp     = (float4*)alloc((size_t)N*16);
  float* h1s      = (float*)alloc((size_t)N*100*4);
  unsigned short* a2h = (unsigned short*)alloc((size_t)NP*128*2);
  unsigned short* a2l = (unsigned short*)alloc((size_t)NP*128*2);
  unsigned short* w2th = (unsigned short*)alloc((size_t)224*128*2);
  unsigned short* w2tl = (unsigned short*)alloc((size_t)224*128*2);
  (void)ws_size; (void)n_in;

  hipMemsetAsync(base, 0, zbytes, stream);
  int gE = (E+255)/256;
  k_count<<<gE,256,0,stream>>>(dst, cnt, E);
  int nb = (N+2047)/2048;
  k_scan1<<<nb,256,0,stream>>>(cnt, rowstart, bsum, N);
  k_scan3<<<(N+255)/256,256,0,stream>>>(bsum, cnt, x, rowstart, cursor, dinv, dxp, N, E, nb);
  k_wconv<<<(224*128+255)/256,256,0,stream>>>(W2, w2th, w2tl);
  k_fill<<<gE,256,0,stream>>>(src, dst, cursor, colsrc, E);
  k_l1<<<(N+255)/256,256,0,stream>>>(dxp, rowstart, colsrc, W1, b1, h1s, N);
  k_agg2<<<(N+7)/8,256,0,stream>>>(h1s, rowstart, colsrc, dinv, a2h, a2l, N);
  k_mm2<<<(N+31)/32,128,0,stream>>>(a2h, a2l, w2th, w2tl, b2, batch, pooled, N);
  k_head<<<G,256,0,stream>>>(pooled, batch, W3, b3, W4, b4, out, N);
}

// Round 17
// 184.778 us; speedup vs baseline: 1.0243x; 1.0243x over previous
//
#include <hip/hip_runtime.h>
#include <math.h>

#define WF 64

__device__ __forceinline__ float silu_f(float v){ return v / (1.0f + expf(-v)); }

typedef __attribute__((ext_vector_type(8))) short bf16x8;
typedef __attribute__((ext_vector_type(4))) float f32x4;

__device__ __forceinline__ void bf16split(float v, unsigned short& h, unsigned short& l){
  unsigned int b = __float_as_uint(v);
  unsigned int hh = (b + 0x8000u) >> 16;
  float hf = __uint_as_float(hh << 16);
  float lo = v - hf;
  unsigned int bl = __float_as_uint(lo);
  h = (unsigned short)hh;
  l = (unsigned short)((bl + 0x8000u) >> 16);
}

// ---------- CSR build ----------
__global__ __launch_bounds__(256) void k_count(const int* __restrict__ dst, int* __restrict__ cnt, int E){
  int e = blockIdx.x*blockDim.x + threadIdx.x;
  if (e < E) atomicAdd(&cnt[dst[e]], 1);
}

// block-local exclusive scan over chunks of 2048 (256 thr x 8 items)
__global__ __launch_bounds__(256) void k_scan1(const int* __restrict__ cnt, int* __restrict__ rowstart, int* __restrict__ bsum, int N){
  __shared__ int s[256];
  int tid = threadIdx.x;
  int base = blockIdx.x*2048 + tid*8;
  int loc[8]; int tsum = 0;
#pragma unroll
  for (int j=0;j<8;++j){ int idx=base+j; int v = (idx<N)?cnt[idx]:0; loc[j]=tsum; tsum+=v; }
  s[tid]=tsum; __syncthreads();
  for (int off=1; off<256; off<<=1){
    int v = (tid>=off)? s[tid-off] : 0;
    __syncthreads();
    s[tid] += v;
    __syncthreads();
  }
  int texc = s[tid] - tsum;
  if (tid==255) bsum[blockIdx.x] = s[255];
#pragma unroll
  for (int j=0;j<8;++j){ int idx=base+j; if (idx<N) rowstart[idx] = texc + loc[j]; }
}

// scan3: adds block prefix (from bsum), writes cursor/dinv and dxp = {di, di*x}
__global__ __launch_bounds__(256) void k_scan3(const int* __restrict__ bsum, const int* __restrict__ cnt,
                        const float* __restrict__ x,
                        int* __restrict__ rowstart, int* __restrict__ cursor,
                        float* __restrict__ dinv, float4* __restrict__ dxp,
                        int N, int E, int nb){
  __shared__ int boffs;
  int tid = threadIdx.x;
  int b = (blockIdx.x*blockDim.x) >> 11;   // uniform within block (256 <= 2048)
  if (tid < WF){
    int v = (tid < nb && tid < b) ? bsum[tid] : 0;
#pragma unroll
    for (int off=32; off; off>>=1) v += __shfl_down(v, off);
    if (tid==0) boffs = v;
  }
  __syncthreads();
  int idx = blockIdx.x*blockDim.x + tid;
  if (idx < N){
    int v = rowstart[idx] + boffs;
    rowstart[idx]=v; cursor[idx]=v;
    float di = rsqrtf((float)(cnt[idx]+1));   // +1 self-loop
    dinv[idx] = di;
    float4 o;
    o.x = di;
    o.y = di*x[3*idx+0];
    o.z = di*x[3*idx+1];
    o.w = di*x[3*idx+2];
    dxp[idx] = o;
  }
  if (idx==0) rowstart[N]=E;
}

// fill CSR: minimum scatter — one 4B colsrc write + cursor atomic per edge
__global__ __launch_bounds__(256) void k_fill(const int* __restrict__ src, const int* __restrict__ dst,
                       int* __restrict__ cursor, int* __restrict__ colsrc, int E){
  int e = blockIdx.x*blockDim.x + threadIdx.x;
  if (e < E){
    int d = dst[e];
    int pos = atomicAdd(&cursor[d], 1);
    colsrc[pos] = src[e];
  }
}

// W2 -> transposed bf16 hi/lo planes [224 f][128 k], zero-padded
__global__ __launch_bounds__(256) void k_wconv(const float* __restrict__ W2,
                       unsigned short* __restrict__ w2th, unsigned short* __restrict__ w2tl){
  int idx = blockIdx.x*blockDim.x + threadIdx.x;
  if (idx < 224*128){
    int f = idx >> 7, k = idx & 127;
    float v = (f < 200 && k < 100) ? W2[(size_t)k*200 + f] : 0.f;
    unsigned short h, l;
    bf16split(v, h, l);
    w2th[idx] = h;
    w2tl[idx] = l;
  }
}

// ---------- layer 1: CSR walk over dxp (16B gathers, 4x unroll), then @W1+b1, silu ----------
__global__ __launch_bounds__(256) void k_l1(const float4* __restrict__ dxp,
                     const int* __restrict__ rowstart, const int* __restrict__ colsrc,
                     const float* __restrict__ W1, const float* __restrict__ b1,
                     float* __restrict__ h1s, int N){
  __shared__ float w[300];
  __shared__ float bb[100];
  int tid = threadIdx.x;
  for (int t=tid; t<300; t+=blockDim.x) w[t]=W1[t];
  for (int t=tid; t<100; t+=blockDim.x) bb[t]=b1[t];
  __syncthreads();
  int i = blockIdx.x*blockDim.x + tid;
  if (i >= N) return;
  float4 self = dxp[i];
  float di = self.x;
  float sx = self.y, sy = self.z, sz = self.w;
  int jb = rowstart[i], je = rowstart[i+1];
  int j = jb;
  for (; j+3 < je; j += 4){
    float4 r0 = dxp[colsrc[j]];
    float4 r1 = dxp[colsrc[j+1]];
    float4 r2 = dxp[colsrc[j+2]];
    float4 r3 = dxp[colsrc[j+3]];
    sx += (r0.y + r1.y) + (r2.y + r3.y);
    sy += (r0.z + r1.z) + (r2.z + r3.z);
    sz += (r0.w + r1.w) + (r2.w + r3.w);
  }
  for (; j < je; ++j){
    float4 r = dxp[colsrc[j]];
    sx += r.y; sy += r.z; sz += r.w;
  }
  sx*=di; sy*=di; sz*=di;
  float* orow = h1s + (size_t)i*100;
#pragma unroll
  for (int f0=0; f0<100; f0+=4){
    float4 o;
    o.x = silu_f(sx*w[f0+0] + sy*w[100+f0+0] + sz*w[200+f0+0] + bb[f0+0]);
    o.y = silu_f(sx*w[f0+1] + sy*w[100+f0+1] + sz*w[200+f0+1] + bb[f0+1]);
    o.z = silu_f(sx*w[f0+2] + sy*w[100+f0+2] + sz*w[200+f0+2] + bb[f0+2]);
    o.w = silu_f(sx*w[f0+3] + sy*w[100+f0+3] + sz*w[200+f0+3] + bb[f0+3]);
    *(float4*)&orow[f0] = o;
  }
}

// ---------- layer 2 aggregation -> bf16 hi/lo planes [N_pad][128] ----------
// HALF-WAVE per node: lanes 0..24 own 4 feats (float4 gather per neighbor);
// lanes 25..31 zero-fill the k=100..127 pad. Split fused here (once/element).
__global__ __launch_bounds__(256) void k_agg2(const float* __restrict__ h1s, const int* __restrict__ rowstart,
                       const int* __restrict__ colsrc, const float* __restrict__ dinv,
                       unsigned short* __restrict__ a2h, unsigned short* __restrict__ a2l, int N){
  int node = blockIdx.x*8 + (threadIdx.x >> 5);
  int lane = threadIdx.x & 31;
  if (node >= N) return;
  if (lane >= 25){
    int ko = 100 + (lane-25)*4;
    ushort4 z = make_ushort4(0,0,0,0);
    *(ushort4*)(a2h + (size_t)node*128 + ko) = z;
    *(ushort4*)(a2l + (size_t)node*128 + ko) = z;
    return;
  }
  float di = dinv[node];
  float4 v = *(const float4*)(h1s + (size_t)node*100 + lane*4);
  float4 acc;
  acc.x = di*v.x; acc.y = di*v.y; acc.z = di*v.z; acc.w = di*v.w;
  int jb = rowstart[node], je = rowstart[node+1];
  int j = jb;
  for (; j+1 < je; j += 2){
    int u0 = colsrc[j];   float w0 = dinv[u0];
    int u1 = colsrc[j+1]; float w1 = dinv[u1];
    float4 r0 = *(const float4*)(h1s + (size_t)u0*100 + lane*4);
    float4 r1 = *(const float4*)(h1s + (size_t)u1*100 + lane*4);
    acc.x += w0*r0.x + w1*r1.x;
    acc.y += w0*r0.y + w1*r1.y;
    acc.z += w0*r0.z + w1*r1.z;
    acc.w += w0*r0.w + w1*r1.w;
  }
  if (j < je){
    int u = colsrc[j]; float wv = dinv[u];
    float4 r = *(const float4*)(h1s + (size_t)u*100 + lane*4);
    acc.x += wv*r.x; acc.y += wv*r.y; acc.z += wv*r.z; acc.w += wv*r.w;
  }
  float o[4] = { di*acc.x, di*acc.y, di*acc.z, di*acc.w };
  ushort4 h4, l4;
  bf16split(o[0], h4.x, l4.x);
  bf16split(o[1], h4.y, l4.y);
  bf16split(o[2], h4.z, l4.z);
  bf16split(o[3], h4.w, l4.w);
  *(ushort4*)(a2h + (size_t)node*128 + lane*4) = h4;
  *(ushort4*)(a2l + (size_t)node*128 + lane*4) = l4;
}

// ---------- layer 2 matmul via split-bf16 MFMA, A once, ONE epilogue ----------
// Block 128 thr = 2 waves, tile 32n. Lane holds A frags (32 VGPR) AND all 7
// f-tiles' accumulators (14 x f32x4 = 56 VGPR) across an unrolled fb loop of
// pure MFMA+W-loads (no barriers). ONE epilogue: plL[8 graphs][224 f] (7KB),
// 3 syncs total (vs 21), one run-length pass, one flush. XCD-swizzled grid.
__global__ __launch_bounds__(128) void k_mm2(const unsigned short* __restrict__ a2h,
                      const unsigned short* __restrict__ a2l,
                      const unsigned short* __restrict__ w2th,
                      const unsigned short* __restrict__ w2tl,
                      const float* __restrict__ b2, const int* __restrict__ batch,
                      float* __restrict__ pooled, int N, int nwg){
  __shared__ float plL[8*224];
  int tid = threadIdx.x;
  int l = tid & 63, w = tid >> 6;   // w in {0,1}
  // bijective XCD swizzle: blocks sharing L2 get adjacent A ranges
  int orig = blockIdx.x;
  int q = nwg >> 3, r = nwg & 7;
  int xcd = orig % 8, rk = orig / 8;
  int bid = (xcd < r) ? (xcd*(q+1) + rk) : (r*(q+1) + (xcd-r)*q + rk);
  int n0 = bid * 32;
  int row = l & 15;
  int kg  = l >> 4;

  const unsigned short* ah_p = a2h + (size_t)(n0 + w*16 + row)*128;
  const unsigned short* al_p = a2l + (size_t)(n0 + w*16 + row)*128;

  bf16x8 ahf[4], alf[4];
#pragma unroll
  for (int ks = 0; ks < 4; ++ks){
    int ko = ks*32 + kg*8;
    ahf[ks] = *(const bf16x8*)(ah_p + ko);
    alf[ks] = *(const bf16x8*)(al_p + ko);
  }

  f32x4 accs[14];
#pragma unroll
  for (int i=0;i<14;++i) accs[i] = (f32x4){0.f,0.f,0.f,0.f};

#pragma unroll
  for (int fb = 0; fb < 7; ++fb){
    int gf0 = fb*32 + row, gf1 = gf0 + 16;
    const unsigned short* wh0_p = w2th + (size_t)gf0*128;
    const unsigned short* wl0_p = w2tl + (size_t)gf0*128;
    const unsigned short* wh1_p = w2th + (size_t)gf1*128;
    const unsigned short* wl1_p = w2tl + (size_t)gf1*128;
    f32x4 a0 = accs[2*fb], a1 = accs[2*fb+1];
#pragma unroll
    for (int ks = 0; ks < 4; ++ks){
      int ko = ks*32 + kg*8;
      bf16x8 wh0 = *(const bf16x8*)(wh0_p + ko);
      bf16x8 wl0 = *(const bf16x8*)(wl0_p + ko);
      bf16x8 wh1 = *(const bf16x8*)(wh1_p + ko);
      bf16x8 wl1 = *(const bf16x8*)(wl1_p + ko);
      a0 = __builtin_amdgcn_mfma_f32_16x16x32_bf16(ahf[ks], wh0, a0, 0, 0, 0);
      a0 = __builtin_amdgcn_mfma_f32_16x16x32_bf16(ahf[ks], wl0, a0, 0, 0, 0);
      a0 = __builtin_amdgcn_mfma_f32_16x16x32_bf16(alf[ks], wh0, a0, 0, 0, 0);
      a1 = __builtin_amdgcn_mfma_f32_16x16x32_bf16(ahf[ks], wh1, a1, 0, 0, 0);
      a1 = __builtin_amdgcn_mfma_f32_16x16x32_bf16(ahf[ks], wl1, a1, 0, 0, 0);
      a1 = __builtin_amdgcn_mfma_f32_16x16x32_bf16(alf[ks], wh1, a1, 0, 0, 0);
    }
    accs[2*fb] = a0; accs[2*fb+1] = a1;
  }

  // ---- single epilogue: silu + LDS pooled window [8][224] -> atomics ----
  for (int idx = tid; idx < 8*224; idx += 128) plL[idx] = 0.f;
  __syncthreads();

  int g0 = batch[n0];
#pragma unroll
  for (int ft = 0; ft < 14; ++ft){
    f32x4 a = accs[ft];
    int gf = (ft >> 1)*32 + (ft & 1)*16 + row;   // f in [0,224)
    if (gf < 200){
      float bias = b2[gf];
      float s = 0.f;
      int gprev = -1;
#pragma unroll
      for (int r2 = 0; r2 < 4; ++r2){
        int node = n0 + w*16 + kg*4 + r2;   // C/D row = (l>>4)*4 + r2
        if (node < N){
          int g = batch[node];
          if (g != gprev){
            if (gprev >= 0){
              int dg = gprev - g0;
              if (dg < 8) atomicAdd(&plL[dg*224 + gf], s);
              else        atomicAdd(&pooled[(size_t)gprev*200 + gf], s);
            }
            gprev = g; s = 0.f;
          }
          s += silu_f(a[r2] + bias);
        }
      }
      if (gprev >= 0){
        int dg = gprev - g0;
        if (dg < 8) atomicAdd(&plL[dg*224 + gf], s);
        else        atomicAdd(&pooled[(size_t)gprev*200 + gf], s);
      }
    }
  }
  __syncthreads();
  for (int idx = tid; idx < 8*224; idx += 128){
    float v = plL[idx];
    if (v != 0.f){
      int r2 = idx / 224, f = idx - r2*224;
      if (f < 200) atomicAdd(&pooled[(size_t)(g0+r2)*200 + f], v);
    }
  }
}

// ---------- head: mean finalize + MLP, one block per graph ----------
__global__ __launch_bounds__(256) void k_head(const float* __restrict__ pooled, const int* __restrict__ batch,
                       const float* __restrict__ W3, const float* __restrict__ b3,
                       const float* __restrict__ W4, const float* __restrict__ b4,
                       float* __restrict__ out, int N){
  __shared__ float pl[200];
  __shared__ float h3[100];
  int g = blockIdx.x; int tid = threadIdx.x;
  // lower_bound(batch, g) and lower_bound(batch, g+1) to get node count
  int lo=0, hi=N;
  while (lo<hi){ int m=(lo+hi)>>1; if (batch[m] < g) lo=m+1; else hi=m; }
  int s = lo;
  hi=N;
  while (lo<hi){ int m=(lo+hi)>>1; if (batch[m] < g+1) lo=m+1; else hi=m; }
  int e = lo;
  float inv = (e>s) ? 1.0f/(float)(e-s) : 0.0f;
  if (tid < 200) pl[tid] = pooled[(size_t)g*200 + tid] * inv;
  __syncthreads();
  if (tid < 100){
    float acc = b3[tid];
    for (int k=0;k<200;++k) acc += pl[k]*W3[k*100+tid];
    h3[tid] = silu_f(acc);
  }
  __syncthreads();
  if (tid < WF){
    float p = 0.f;
    if (tid < 100)      p  = h3[tid]     * W4[tid];
    if (tid + 64 < 100) p += h3[tid+64]  * W4[tid+64];
#pragma unroll
    for (int off=32; off; off>>=1) p += __shfl_down(p, off);
    if (tid==0) out[g] = p + b4[0];
  }
}

extern "C" void kernel_launch(void* const* d_in, const int* in_sizes, int n_in,
                              void* d_out, int out_size, void* d_ws, size_t ws_size,
                              hipStream_t stream){
  const float* x  = (const float*)d_in[0];
  const int*   ei = (const int*)  d_in[1];
  const int* batch= (const int*)  d_in[2];
  const float* W1 = (const float*)d_in[4];
  const float* b1 = (const float*)d_in[5];
  const float* W2 = (const float*)d_in[6];
  const float* b2 = (const float*)d_in[7];
  const float* W3 = (const float*)d_in[8];
  const float* b3 = (const float*)d_in[9];
  const float* W4 = (const float*)d_in[10];
  const float* b4 = (const float*)d_in[11];
  float* out = (float*)d_out;

  int N = in_sizes[0]/3;
  int E = in_sizes[1]/2;
  int G = out_size;
  const int* src = ei;
  const int* dst = ei + E;
  int NP = ((N + 63)/64)*64;   // padded rows for mm2 tile overrun

  char* base = (char*)d_ws; size_t off = 0;
  auto alloc = [&](size_t bytes)->void*{
    void* p = base + off;
    off = (off + bytes + 255) & ~(size_t)255;
    return p;
  };
  // zero-init group first (single memset): cnt, pooled
  int*   cnt      = (int*)  alloc((size_t)N*4);
  float* pooled   = (float*)alloc((size_t)G*200*4);
  size_t zbytes   = off;
  int*   rowstart = (int*)  alloc((size_t)(N+1)*4);
  int*   cursor   = (int*)  alloc((size_t)N*4);
  int*   bsum     = (int*)  alloc(4096);
  int*   colsrc   = (int*)  alloc((size_t)E*4);
  float* dinv     = (float*)alloc((size_t)N*4);
  float4* dxp     = (float4*)alloc((size_t)N*16);
  float* h1s      = (float*)alloc((size_t)N*100*4);
  unsigned short* a2h = (unsigned short*)alloc((size_t)NP*128*2);
  unsigned short* a2l = (unsigned short*)alloc((size_t)NP*128*2);
  unsigned short* w2th = (unsigned short*)alloc((size_t)224*128*2);
  unsigned short* w2tl = (unsigned short*)alloc((size_t)224*128*2);
  (void)ws_size; (void)n_in;

  hipMemsetAsync(base, 0, zbytes, stream);
  int gE = (E+255)/256;
  k_count<<<gE,256,0,stream>>>(dst, cnt, E);
  int nb = (N+2047)/2048;
  k_scan1<<<nb,256,0,stream>>>(cnt, rowstart, bsum, N);
  k_scan3<<<(N+255)/256,256,0,stream>>>(bsum, cnt, x, rowstart, cursor, dinv, dxp, N, E, nb);
  k_wconv<<<(224*128+255)/256,256,0,stream>>>(W2, w2th, w2tl);
  k_fill<<<gE,256,0,stream>>>(src, dst, cursor, colsrc, E);
  k_l1<<<(N+255)/256,256,0,stream>>>(dxp, rowstart, colsrc, W1, b1, h1s, N);
  k_agg2<<<(N+7)/8,256,0,stream>>>(h1s, rowstart, colsrc, dinv, a2h, a2l, N);
  int nwg = (N+31)/32;
  k_mm2<<<nwg,128,0,stream>>>(a2h, a2l, w2th, w2tl, b2, batch, pooled, N, nwg);
  k_head<<<G,256,0,stream>>>(pooled, batch, W3, b3, W4, b4, out, N);
}